// Round 4
// baseline (160.003 us; speedup 1.0000x reference)
//
#include <hip/hip_runtime.h>

typedef __attribute__((ext_vector_type(8))) short short8;
typedef __attribute__((ext_vector_type(4))) float floatx4;
typedef __attribute__((ext_vector_type(4))) unsigned short ushortx4;
typedef unsigned int u32;

#define MFMA_BF16(A, Bv, C) __builtin_amdgcn_mfma_f32_16x16x32_bf16(A, Bv, C, 0, 0, 0)

#if __has_builtin(__builtin_amdgcn_exp2f)
#define EXP2(x) __builtin_amdgcn_exp2f(x)
#else
#define EXP2(x) exp2f(x)
#endif

__device__ __forceinline__ unsigned short f2bf(float f) {  // RNE
  unsigned int u = __builtin_bit_cast(unsigned int, f);
  u += 0x7FFFu + ((u >> 16) & 1u);
  return (unsigned short)(u >> 16);
}
__device__ __forceinline__ unsigned short f2bf_trunc(float f) {  // bias cancels in P/l ratio
  return (unsigned short)(__builtin_bit_cast(unsigned int, f) >> 16);
}
// async 16B/lane global->LDS: lds dst = uniform base + lane*16
__device__ __forceinline__ void load_lds16(const void* g, void* l) {
  __builtin_amdgcn_global_load_lds((const __attribute__((address_space(1))) u32*)g,
                                   (__attribute__((address_space(3))) u32*)l, 16, 0, 0);
}

// Prep: blocks 0-511 convert K fp32->bf16; blocks 512-1023 transpose V -> Vt[b][d][s] bf16.
__global__ __launch_bounds__(256) void prep_kv(
    const float* __restrict__ k, const float* __restrict__ v,
    unsigned short* __restrict__ kb, unsigned short* __restrict__ vt) {
  __shared__ float tile[64 * 68];
  int blk = blockIdx.x;
  int t = threadIdx.x;
  if (blk < 512) {
    size_t base = (size_t)blk * 4096 + t * 4;
#pragma unroll
    for (int i = 0; i < 4; i++) {
      size_t off = base + (size_t)i * 1024;
      floatx4 f = *(const floatx4*)(k + off);
      ushortx4 h;
      h[0] = f2bf(f[0]); h[1] = f2bf(f[1]); h[2] = f2bf(f[2]); h[3] = f2bf(f[3]);
      *(ushortx4*)(kb + off) = h;
    }
  } else {
    blk -= 512;
    int b = blk >> 6, si = blk & 63;
    int r = t >> 2, c4 = (t & 3) * 16;
    const float* vp = v + ((size_t)b * 4096 + si * 64 + r) * 64 + c4;
#pragma unroll
    for (int i = 0; i < 4; i++)
      *(floatx4*)(tile + r * 68 + c4 + i * 4) = *(const floatx4*)(vp + i * 4);
    __syncthreads();
    unsigned short* vo = vt + ((size_t)b * 64 + r) * 4096 + si * 64 + c4;
#pragma unroll
    for (int i = 0; i < 4; i++) {
      ushortx4 h;
#pragma unroll
      for (int j = 0; j < 4; j++) h[j] = f2bf(tile[(c4 + i * 4 + j) * 68 + r]);
      *(ushortx4*)(vo + i * 4) = h;
    }
  }
}

// Attention: 512 blocks x 256 thr. Block = 64 q-rows; per 128-key tile each wave owns a
// private 32-key window x ALL 64 q (K/V LDS fragments read once, no duplication).
// S^T = K*Q^T so the C-layout (col=q, rows=keys) lets P writes be b64 AND P A-frag reads
// b128 (both sides of the transpose vectorized). l via ones-MFMA. O/l merged once at end.
__global__ __launch_bounds__(256, 2) void attn(
    const float* __restrict__ q, const unsigned short* __restrict__ kb,
    const unsigned short* __restrict__ vt, const float* __restrict__ mask,
    float* __restrict__ out) {
  // ushort units: ldsK [0,8192): 128keys x 64d (swizzled); ldsV [8192,16384): 64d x 128keys
  // (swizzled); P [16384,26624): per-wave 64q x 40 (stride 80B). Total 53248 B.
  __shared__ __align__(16) unsigned short smem[26624];
  const int tid = threadIdx.x;
  const int wave = tid >> 6, lane = tid & 63;
  const int c = lane & 15, quad = lane >> 4;
  const int b = blockIdx.x & 7, qt = blockIdx.x >> 3;  // blk%8=batch -> per-XCD K/V L2 locality
  const int q0 = qt * 64;

  const unsigned short* kB = kb + (size_t)b * (4096 * 64);
  const unsigned short* vB = vt + (size_t)b * (64 * 4096);

  // Q B-frags (B[k=d][n=q]), loop-invariant; fold (1/8)*log2(e) -> log2-domain scores
  const float qscale = 0.18033688011112042f;
  short8 qf[4][2];
#pragma unroll
  for (int nt = 0; nt < 4; nt++)
#pragma unroll
    for (int kc = 0; kc < 2; kc++) {
      const float* qp = q + ((size_t)b * 4096 + q0 + nt * 16 + c) * 64 + kc * 32 + quad * 8;
      floatx4 f0 = *(const floatx4*)qp;
      floatx4 f1 = *(const floatx4*)(qp + 4);
      short8 s;
#pragma unroll
      for (int j = 0; j < 4; j++) {
        s[j] = (short)f2bf(f0[j] * qscale);
        s[4 + j] = (short)f2bf(f1[j] * qscale);
      }
      qf[nt][kc] = s;
    }

  floatx4 o[4][4], ol[4];
#pragma unroll
  for (int mt = 0; mt < 4; mt++) {
    ol[mt] = (floatx4){0.f, 0.f, 0.f, 0.f};
#pragma unroll
    for (int nt = 0; nt < 4; nt++) o[mt][nt] = (floatx4){0.f, 0.f, 0.f, 0.f};
  }

  short8 ones;  // B=ones => every C column = row-sum (free l)
#pragma unroll
  for (int j = 0; j < 8; j++) ones[j] = (short)0x3F80;

  unsigned short* ldsK = smem;
  unsigned short* ldsV = smem + 8192;
  unsigned short* P = smem + 16384 + wave * 2560;  // [64 q][40] (32 keys + 8 pad)

  const int r8 = lane >> 3, cs8 = lane & 7;  // K staging: 8 rows x 8 slots per instr
  const int rv = lane >> 4, sv = lane & 15;  // V staging: 4 rows x 16 slots per instr

  auto stage = [&](int t) {
    const int key0 = t * 128;
#pragma unroll
    for (int i = 0; i < 4; i++) {  // K: physical slot = src slot ^ (row&7)
      const int rows0 = (wave * 4 + i) * 8;
      load_lds16(kB + (size_t)(key0 + rows0 + r8) * 64 + (cs8 ^ r8) * 8, ldsK + rows0 * 64);
    }
#pragma unroll
    for (int i = 0; i < 4; i++) {  // V: swizzle low-3 slot bits by d&7
      const int d0 = (wave * 4 + i) * 4;
      const int d = d0 + rv;
      const int ss = (sv & 8) | ((sv ^ (d & 7)) & 7);
      load_lds16(vB + (size_t)d * 4096 + key0 + ss * 8, ldsV + d0 * 128);
    }
  };

  stage(0);

  for (int t = 0; t < 32; t++) {
    __syncthreads();  // staged tile visible (vmcnt drain)

    const int wk = wave * 32;  // wave's private key window

    // K A-frags (A[m=key][k=d]): src slot 4*kc+quad, physical ^= row&7 (= c&7)
    short8 kf[2][2];
#pragma unroll
    for (int mt = 0; mt < 2; mt++)
#pragma unroll
      for (int kc = 0; kc < 2; kc++)
        kf[mt][kc] =
            *(const short8*)(ldsK + (wk + mt * 16 + c) * 64 + ((kc * 4 + quad) ^ (c & 7)) * 8);

    // S^T tiles: rows=keys, col=q -> exp2 -> b64 write (4 consecutive keys) into P[q][key]
#pragma unroll
    for (int nt = 0; nt < 4; nt++)
#pragma unroll
      for (int mt = 0; mt < 2; mt++) {
        floatx4 s = (floatx4){0.f, 0.f, 0.f, 0.f};
        s = MFMA_BF16(kf[mt][0], qf[nt][0], s);
        s = MFMA_BF16(kf[mt][1], qf[nt][1], s);
        ushortx4 pk;
#pragma unroll
        for (int r = 0; r < 4; r++) pk[r] = f2bf_trunc(EXP2(s[r]));
        *(ushortx4*)(P + (nt * 16 + c) * 40 + mt * 16 + quad * 4) = pk;
      }

    // V B-frags (B[k=key][n=d]) + P A-frags (A[m=q][k=key]) -- all b128
    short8 vf[4], pf[4];
#pragma unroll
    for (int nt = 0; nt < 4; nt++) {
      const int d = nt * 16 + c;
      const int s = wave * 4 + quad;  // src key-slot within 128-key tile
      const int ps = (s & 8) | ((s ^ (d & 7)) & 7);
      vf[nt] = *(const short8*)(ldsV + d * 128 + ps * 8);
    }
#pragma unroll
    for (int mt = 0; mt < 4; mt++)
      pf[mt] = *(const short8*)(P + (mt * 16 + c) * 40 + quad * 8);

#pragma unroll
    for (int mt = 0; mt < 4; mt++) {
#pragma unroll
      for (int nt = 0; nt < 4; nt++) o[mt][nt] = MFMA_BF16(pf[mt], vf[nt], o[mt][nt]);
      ol[mt] = MFMA_BF16(pf[mt], ones, ol[mt]);
    }

    __syncthreads();  // all reads of this tile done -> safe to restage
    if (t + 1 < 32) stage(t + 1);
  }

  // Merge 4 wave-partials once: wave0 stores, waves 1-3 atomicAdd (LDS reused as fp32 obuf)
  __syncthreads();
  float* obuf = (float*)smem;         // [64][68]
  float* lbuf = (float*)smem + 4352;  // [64]
  if (wave == 0) {
#pragma unroll
    for (int mt = 0; mt < 4; mt++) {
#pragma unroll
      for (int nt = 0; nt < 4; nt++)
#pragma unroll
        for (int r = 0; r < 4; r++)
          obuf[(mt * 16 + quad * 4 + r) * 68 + nt * 16 + c] = o[mt][nt][r];
      if (c == 0)
#pragma unroll
        for (int r = 0; r < 4; r++) lbuf[mt * 16 + quad * 4 + r] = ol[mt][r];
    }
  }
  __syncthreads();
  if (wave != 0) {
#pragma unroll
    for (int mt = 0; mt < 4; mt++) {
#pragma unroll
      for (int nt = 0; nt < 4; nt++)
#pragma unroll
        for (int r = 0; r < 4; r++)
          atomicAdd(&obuf[(mt * 16 + quad * 4 + r) * 68 + nt * 16 + c], o[mt][nt][r]);
      if (c == 0)
#pragma unroll
        for (int r = 0; r < 4; r++) atomicAdd(&lbuf[mt * 16 + quad * 4 + r], ol[mt][r]);
    }
  }
  __syncthreads();

  // out = O/l * mask, coalesced float4 stores
  const int row = tid >> 2, dg = (tid & 3) * 16;
  const float sc = mask[b * 4096 + q0 + row] / lbuf[row];
  float* op = out + ((size_t)b * 4096 + q0 + row) * 64 + dg;
#pragma unroll
  for (int i = 0; i < 4; i++) {
    floatx4 a = *(const floatx4*)(obuf + row * 68 + dg + i * 4);
    *(floatx4*)(op + i * 4) = a * sc;
  }
}

extern "C" void kernel_launch(void* const* d_in, const int* in_sizes, int n_in,
                              void* d_out, int out_size, void* d_ws, size_t ws_size,
                              hipStream_t stream) {
  const float* q = (const float*)d_in[0];
  const float* k = (const float*)d_in[1];
  const float* v = (const float*)d_in[2];
  const float* mask = (const float*)d_in[3];
  unsigned short* kb = (unsigned short*)d_ws;  // 4 MB
  unsigned short* vt = kb + 8 * 4096 * 64;     // 4 MB (needs ws >= 8 MB)
  prep_kv<<<1024, 256, 0, stream>>>(k, v, kb, vt);
  attn<<<512, 256, 0, stream>>>(q, kb, vt, mask, (float*)d_out);
}

// Round 6
// 127.854 us; speedup vs baseline: 1.2515x; 1.2515x over previous
//
#include <hip/hip_runtime.h>

typedef __attribute__((ext_vector_type(8))) short short8;
typedef __attribute__((ext_vector_type(4))) short short4v;
typedef __attribute__((ext_vector_type(4))) float floatx4;
typedef __attribute__((ext_vector_type(4))) unsigned short ushortx4;
typedef __attribute__((ext_vector_type(8))) unsigned short ushortx8;
typedef unsigned int u32;
typedef __attribute__((ext_vector_type(2))) u32 u32x2;
typedef __attribute__((ext_vector_type(4))) u32 u32x4;

#define MFMA_K32(A, B, C) __builtin_amdgcn_mfma_f32_16x16x32_bf16(A, B, C, 0, 0, 0)

#if __has_builtin(__builtin_amdgcn_mfma_f32_16x16x16bf16_1k)
#define HAVE_K16 1
#define MFMA_K16(A, B, C) __builtin_amdgcn_mfma_f32_16x16x16bf16_1k(A, B, C, 0, 0, 0)
#else
#define HAVE_K16 0  // fallback: zero-padded K32 (upper 4 k-slots = 0; layout-consistent)
#endif

#if __has_builtin(__builtin_amdgcn_exp2f)
#define EXP2(x) __builtin_amdgcn_exp2f(x)
#else
#define EXP2(x) exp2f(x)
#endif

__device__ __forceinline__ unsigned short f2bf(float f) {  // RNE
  u32 u = __builtin_bit_cast(u32, f);
  u += 0x7FFFu + ((u >> 16) & 1u);
  return (unsigned short)(u >> 16);
}
// async 16B/lane global->LDS: lds dst = uniform base + lane*16
__device__ __forceinline__ void load_lds16(const void* g, void* l) {
  __builtin_amdgcn_global_load_lds((const __attribute__((address_space(1))) u32*)g,
                                   (__attribute__((address_space(3))) u32*)l, 16, 0, 0);
}

// Prep: blk<512: K fp32->bf16 (coalesced). blk>=512: V -> Vt_g[b][tile][d][64keys],
// bf16, tile-chunked AND pre-swizzled (16B slot p of row d holds keys (p^(d&7))*8..+7)
// so attn's V staging is an identity lane-linear copy. All global R/W coalesced.
__global__ __launch_bounds__(256) void prep_kv(
    const float* __restrict__ k, const float* __restrict__ v,
    unsigned short* __restrict__ kb, unsigned short* __restrict__ vt) {
  __shared__ float tileT[64 * 68];  // [d][key] fp32
  int blk = blockIdx.x;
  int t = threadIdx.x;
  if (blk < 512) {
    size_t base = (size_t)blk * 4096 + t * 4;
#pragma unroll
    for (int i = 0; i < 4; i++) {
      size_t off = base + (size_t)i * 1024;
      floatx4 f = *(const floatx4*)(k + off);
      ushortx4 h;
      h[0] = f2bf(f[0]); h[1] = f2bf(f[1]); h[2] = f2bf(f[2]); h[3] = f2bf(f[3]);
      *(ushortx4*)(kb + off) = h;
    }
  } else {
    blk -= 512;
    const int b = blk >> 6, si = blk & 63;
    const int r = t >> 2, c4 = (t & 3) * 16;  // r = key-in-tile, c4 = d-chunk
    const float* vp = v + ((size_t)b * 4096 + si * 64 + r) * 64 + c4;
#pragma unroll
    for (int i = 0; i < 4; i++) {
      floatx4 f = *(const floatx4*)(vp + i * 4);
#pragma unroll
      for (int j = 0; j < 4; j++) tileT[(c4 + i * 4 + j) * 68 + r] = f[j];  // transpose
    }
    __syncthreads();
    unsigned short* vo = vt + ((size_t)b * 64 + si) * 4096;  // tile si base (64x64)
#pragma unroll
    for (int i = 0; i < 2; i++) {
      const int u = t + i * 256;
      const int d = u >> 3, p = u & 7;        // phys 16B slot
      const int s = p ^ (d & 7);              // logical slot
      const float* src = tileT + d * 68 + s * 8;
      floatx4 f0 = *(const floatx4*)src;
      floatx4 f1 = *(const floatx4*)(src + 4);
      ushortx8 h;
#pragma unroll
      for (int j = 0; j < 4; j++) { h[j] = f2bf(f0[j]); h[4 + j] = f2bf(f1[j]); }
      *(ushortx8*)(vo + d * 64 + p * 8) = h;  // wave writes 1KB contiguous
    }
  }
}

// Attention: 512 blocks x 256 thr (4 waves), 64-key tiles double-buffered (32KB),
// wave-private 16-key window x all 64 q. S^T = K*Q^T: the QK C-layout IS the K16
// B-frag layout of P^T -> PV goes register-direct (no P LDS round-trip, no barrier
// between QK and PV). l per (lane, q-tile) in VALU (truncation-consistent), shfl-reduced.
__global__ __launch_bounds__(256, 3) void attn(
    const float* __restrict__ q, const unsigned short* __restrict__ kb,
    const unsigned short* __restrict__ vt, const float* __restrict__ mask,
    float* __restrict__ out) {
  // loop (ushort): buf0 K[0,4096) V[4096,8192); buf1 [8192,16384)  = 32KB
  // epilogue (float): obuf0 [0,4608) obuf1 [4608,9216) stride 72; lbuf [9216,9472)
  __shared__ __align__(16) char smem_raw[37888];
  unsigned short* smem = (unsigned short*)smem_raw;
  const int tid = threadIdx.x;
  const int wave = tid >> 6, lane = tid & 63;
  const int c = lane & 15, quad = lane >> 4;
  const int b = blockIdx.x & 7, qt = blockIdx.x >> 3;  // blk%8=batch -> per-XCD L2 locality
  const int q0 = qt * 64;

  const unsigned short* kB = kb + (size_t)b * (4096 * 64);
  const unsigned short* vtB = vt + (size_t)b * (64 * 4096);

  // Q B-frags (B[k=d=kc*32+quad*8+j][n=q=c]), loop-invariant, scale folds log2-domain
  const float qscale = 0.18033688011112042f;
  short8 qf[4][2];
#pragma unroll
  for (int nt = 0; nt < 4; nt++)
#pragma unroll
    for (int kc = 0; kc < 2; kc++) {
      const float* qp = q + ((size_t)b * 4096 + q0 + nt * 16 + c) * 64 + kc * 32 + quad * 8;
      floatx4 f0 = *(const floatx4*)qp;
      floatx4 f1 = *(const floatx4*)(qp + 4);
      short8 s;
#pragma unroll
      for (int j = 0; j < 4; j++) {
        s[j] = (short)f2bf(f0[j] * qscale);
        s[4 + j] = (short)f2bf(f1[j] * qscale);
      }
      qf[nt][kc] = s;
    }

  floatx4 o[4][4];  // o[mt=d-tile][nt=q-tile]: O^T[d=mt*16+quad*4+r][q=nt*16+c]
#pragma unroll
  for (int mt = 0; mt < 4; mt++)
#pragma unroll
    for (int nt = 0; nt < 4; nt++) o[mt][nt] = (floatx4){0.f, 0.f, 0.f, 0.f};
  // llane[nt]: partial sum of P^T[key][q=nt*16+c] over this (wave,quad)'s keys.
  // ONE ACCUMULATOR PER Q-TILE (r5 bug: collapsing nt mixed 4 different queries).
  float llane[4] = {0.f, 0.f, 0.f, 0.f};

  const int r8 = lane >> 3, cs8 = lane & 7;  // staging lane split
  const int cl7 = c & 7;

  auto stage = [&](int t, int buf) {
    unsigned short* dK = smem + buf * 8192;
    unsigned short* dV = dK + 4096;
    const unsigned short* gK = kB + (size_t)(t * 64) * 64;
    const unsigned short* gV = vtB + (size_t)t * 4096;
#pragma unroll
    for (int j = 0; j < 2; j++) {
      const int i = wave * 2 + j;  // wave-uniform chunk (8 rows = 1KB)
      load_lds16(gK + (i * 8 + r8) * 64 + (cs8 ^ r8) * 8, dK + i * 512);
      load_lds16(gV + i * 512 + lane * 8, dV + i * 512);  // identity (pre-swizzled)
    }
  };

  stage(0, 0);
  __syncthreads();

  for (int t = 0; t < 64; t++) {
    if (t + 1 < 64) stage(t + 1, (t + 1) & 1);  // async, overlaps compute below

    const unsigned short* K = smem + (t & 1) * 8192;
    const unsigned short* Vt = K + 4096;

    // K A-frags: A[m=key=c (window wave*16)][k=d]; phys slot = (kc*4+quad)^(row&7)
    short8 kf[2];
#pragma unroll
    for (int kc = 0; kc < 2; kc++)
      kf[kc] = *(const short8*)(K + (wave * 16 + c) * 64 + ((kc * 4 + quad) ^ cl7) * 8);

    // Vt A-frags (K16): A[m=d=mt*16+c][k=key=quad*4+j]; phys16 = (2w+(quad>>1))^(d&7)
    u32x2 vv[4];
#pragma unroll
    for (int mt = 0; mt < 4; mt++) {
      const int phys = (2 * wave + (quad >> 1)) ^ cl7;
      vv[mt] = *(const u32x2*)(Vt + (mt * 16 + c) * 64 + phys * 8 + (quad & 1) * 4);
    }

#pragma unroll
    for (int nt = 0; nt < 4; nt++) {
      floatx4 s = (floatx4){0.f, 0.f, 0.f, 0.f};
      s = MFMA_K32(kf[0], qf[nt][0], s);
      s = MFMA_K32(kf[1], qf[nt][1], s);
      // P^T[key=quad*4+r][q=nt*16+c] = exp2(s[r]); trunc-to-bf16 (consistent num/denom)
      u32 u0 = __builtin_bit_cast(u32, EXP2(s[0]));
      u32 u1 = __builtin_bit_cast(u32, EXP2(s[1]));
      u32 u2 = __builtin_bit_cast(u32, EXP2(s[2]));
      u32 u3 = __builtin_bit_cast(u32, EXP2(s[3]));
      llane[nt] += __builtin_bit_cast(float, u0 & 0xFFFF0000u) +
                   __builtin_bit_cast(float, u1 & 0xFFFF0000u) +
                   __builtin_bit_cast(float, u2 & 0xFFFF0000u) +
                   __builtin_bit_cast(float, u3 & 0xFFFF0000u);
      u32 plo = __builtin_amdgcn_perm(u1, u0, 0x07060302u);  // [hi16(u1)|hi16(u0)]
      u32 phi = __builtin_amdgcn_perm(u3, u2, 0x07060302u);
#if HAVE_K16
      short4v pf = __builtin_bit_cast(short4v, (u32x2){plo, phi});  // B[k=quad*4+j][n=c]
#pragma unroll
      for (int mt = 0; mt < 4; mt++) {
        short4v va = __builtin_bit_cast(short4v, vv[mt]);
        o[mt][nt] = MFMA_K16(va, pf, o[mt][nt]);
      }
#else
      short8 pf = __builtin_bit_cast(short8, (u32x4){plo, phi, 0u, 0u});
#pragma unroll
      for (int mt = 0; mt < 4; mt++) {
        short8 va = __builtin_bit_cast(short8, (u32x4){vv[mt][0], vv[mt][1], 0u, 0u});
        o[mt][nt] = MFMA_K32(va, pf, o[mt][nt]);
      }
#endif
    }

    __syncthreads();  // drains stage(t+1), closes reads of buf[t&1]
  }

  // l: butterfly-reduce across quads -> every lane holds l_wave[q=nt*16+c]
#pragma unroll
  for (int nt = 0; nt < 4; nt++) {
    llane[nt] += __shfl_xor(llane[nt], 16, 64);
    llane[nt] += __shfl_xor(llane[nt], 32, 64);
  }

  // Merge 4 wave-partials: waves 0,1 store obuf0/1; waves 2,3 add; combine+store.
  float* obuf = (float*)smem_raw;     // 2 x [64 q][72]
  float* lbuf = obuf + 9216;          // [4 waves][64 q]
  if (lane < 16) {
#pragma unroll
    for (int nt = 0; nt < 4; nt++) lbuf[wave * 64 + nt * 16 + c] = llane[nt];
  }
  if (wave < 2) {
    float* ob = obuf + wave * 4608;
#pragma unroll
    for (int mt = 0; mt < 4; mt++)
#pragma unroll
      for (int nt = 0; nt < 4; nt++)
        *(floatx4*)(ob + (nt * 16 + c) * 72 + mt * 16 + quad * 4) = o[mt][nt];
  }
  __syncthreads();
  if (wave >= 2) {
    float* ob = obuf + (wave - 2) * 4608;
#pragma unroll
    for (int mt = 0; mt < 4; mt++)
#pragma unroll
      for (int nt = 0; nt < 4; nt++) {
        float* a = ob + (nt * 16 + c) * 72 + mt * 16 + quad * 4;
        floatx4 cur = *(floatx4*)a;
        *(floatx4*)a = cur + o[mt][nt];
      }
  }
  __syncthreads();

  // out = O/l * mask, coalesced float4 stores
  const int row = tid >> 2, dg = (tid & 3) * 16;
  const float l = lbuf[row] + lbuf[64 + row] + lbuf[128 + row] + lbuf[192 + row];
  const float sc = mask[b * 4096 + q0 + row] / l;
  float* op = out + ((size_t)b * 4096 + q0 + row) * 64 + dg;
#pragma unroll
  for (int i = 0; i < 4; i++) {
    floatx4 a = *(const floatx4*)(obuf + row * 72 + dg + i * 4);
    floatx4 b2 = *(const floatx4*)(obuf + 4608 + row * 72 + dg + i * 4);
    *(floatx4*)(op + i * 4) = (a + b2) * sc;
  }
}

extern "C" void kernel_launch(void* const* d_in, const int* in_sizes, int n_in,
                              void* d_out, int out_size, void* d_ws, size_t ws_size,
                              hipStream_t stream) {
  const float* q = (const float*)d_in[0];
  const float* k = (const float*)d_in[1];
  const float* v = (const float*)d_in[2];
  const float* mask = (const float*)d_in[3];
  unsigned short* kb = (unsigned short*)d_ws;  // 4 MB
  unsigned short* vt = kb + 8 * 4096 * 64;     // 4 MB (needs ws >= 8 MB)
  prep_kv<<<1024, 256, 0, stream>>>(k, v, kb, vt);
  attn<<<512, 256, 0, stream>>>(q, kb, vt, mask, (float*)d_out);
}

// Round 8
// 124.483 us; speedup vs baseline: 1.2853x; 1.0271x over previous
//
#include <hip/hip_runtime.h>

typedef __attribute__((ext_vector_type(8))) short short8;
typedef __attribute__((ext_vector_type(4))) short short4v;
typedef __attribute__((ext_vector_type(4))) float floatx4;
typedef __attribute__((ext_vector_type(4))) unsigned short ushortx4;
typedef __attribute__((ext_vector_type(8))) unsigned short ushortx8;
typedef unsigned int u32;
typedef __attribute__((ext_vector_type(2))) u32 u32x2;
typedef __attribute__((ext_vector_type(4))) u32 u32x4;

#define MFMA_K32(A, B, C) __builtin_amdgcn_mfma_f32_16x16x32_bf16(A, B, C, 0, 0, 0)

#if __has_builtin(__builtin_amdgcn_mfma_f32_16x16x16bf16_1k)
#define HAVE_K16 1
#define MFMA_K16(A, B, C) __builtin_amdgcn_mfma_f32_16x16x16bf16_1k(A, B, C, 0, 0, 0)
#else
#define HAVE_K16 0  // fallback: zero-padded K32 (layout-consistent: same k slots in A and B)
#endif

#if __has_builtin(__builtin_amdgcn_exp2f)
#define EXP2(x) __builtin_amdgcn_exp2f(x)
#else
#define EXP2(x) exp2f(x)
#endif

// gfx9 waitcnt imm: vmcnt[3:0]|expcnt<<4|lgkmcnt<<8|vmcnt[5:4]<<14 (lgkm/exp = no-wait)
#define WAIT_VM4() __builtin_amdgcn_s_waitcnt(0x0F74)  // vmcnt(4)
#define WAIT_VM0() __builtin_amdgcn_s_waitcnt(0x0F70)  // vmcnt(0)

__device__ __forceinline__ unsigned short f2bf(float f) {  // RNE
  u32 u = __builtin_bit_cast(u32, f);
  u += 0x7FFFu + ((u >> 16) & 1u);
  return (unsigned short)(u >> 16);
}
// async 16B/lane global->LDS: lds dst = wave-uniform base + lane*16
__device__ __forceinline__ void load_lds16(const void* g, void* l) {
  __builtin_amdgcn_global_load_lds((const __attribute__((address_space(1))) u32*)g,
                                   (__attribute__((address_space(3))) u32*)l, 16, 0, 0);
}

// Prep (512 blocks): each block converts one 16KB K slab fp32->bf16 (plain layout)
// AND transposes one 64x64 V tile -> vt[b][tile][d][key] bf16 (plain layout).
__global__ __launch_bounds__(256) void prep_kv(
    const float* __restrict__ k, const float* __restrict__ v,
    unsigned short* __restrict__ kb, unsigned short* __restrict__ vt) {
  __shared__ float tileT[64 * 68];  // [d][key]
  const int blk = blockIdx.x, tid = threadIdx.x;
  // K: 4096 consecutive floats x 4
  size_t base = (size_t)blk * 4096 + tid * 4;
#pragma unroll
  for (int i = 0; i < 4; i++) {
    size_t off = base + (size_t)i * 1024;
    floatx4 f = *(const floatx4*)(k + off);
    ushortx4 h;
    h[0] = f2bf(f[0]); h[1] = f2bf(f[1]); h[2] = f2bf(f[2]); h[3] = f2bf(f[3]);
    *(ushortx4*)(kb + off) = h;
  }
  // V tile transpose
  const int r = tid >> 2, c4 = (tid & 3) * 16;  // r = key-in-tile, c4 = d-chunk
  const float* vp = v + ((size_t)blk * 64 + r) * 64 + c4;
#pragma unroll
  for (int i = 0; i < 4; i++) {
    floatx4 f = *(const floatx4*)(vp + i * 4);
#pragma unroll
    for (int j = 0; j < 4; j++) tileT[(c4 + i * 4 + j) * 68 + r] = f[j];
  }
  __syncthreads();
  unsigned short* vo = vt + (size_t)blk * 4096;
#pragma unroll
  for (int i = 0; i < 2; i++) {
    const int u = tid + i * 256;
    const int d = u >> 3, p = u & 7;
    const float* src = tileT + d * 68 + p * 8;
    floatx4 f0 = *(const floatx4*)src;
    floatx4 f1 = *(const floatx4*)(src + 4);
    ushortx8 h;
#pragma unroll
    for (int j = 0; j < 4; j++) { h[j] = f2bf(f0[j]); h[4 + j] = f2bf(f1[j]); }
    *(ushortx8*)(vo + d * 64 + p * 8) = h;
  }
}

// Attention: 512 blocks x 256 thr (4 waves). BARRIER-FREE hot loop: each wave owns a
// private 16-key window per 64-key tile and stages its own K (source-XOR swizzled) + V
// slice into its own LDS double-buffer; sync = wave-local s_waitcnt vmcnt(4) (next
// stage's 4 loads stay in flight). S^T = K*Q^T -> C-layout == K16 B-frag layout -> P
// register-direct into PV; l via ones-A K16 on the same pf (consistent, zero VALU).
__global__ __launch_bounds__(256, 2) void attn(
    const float* __restrict__ q, const unsigned short* __restrict__ kb,
    const unsigned short* __restrict__ vt, const float* __restrict__ mask,
    float* __restrict__ out) {
  // loop: 4 waves x 2 bufs x (K 1024 + V 1024 ushorts) = 32768 B (all wave-private)
  // epilogue: obuf 2x[64][72] fp32 (36864) + lbuf [4][64] (1024) = 37888 B
  __shared__ __align__(16) char smem_raw[37888];
  unsigned short* smem = (unsigned short*)smem_raw;
  const int tid = threadIdx.x;
  const int wave = tid >> 6, lane = tid & 63;
  const int c = lane & 15, quad = lane >> 4;
  const int b = blockIdx.x & 7, qt = blockIdx.x >> 3;  // blk%8=batch -> per-XCD L2 locality
  const int q0 = qt * 64;

  const unsigned short* kB = kb + (size_t)b * (4096 * 64);
  const unsigned short* vtB = vt + (size_t)b * (64 * 4096);

  // Q B-frags (B[k=d=kc*32+quad*8+j][n=q=c]), loop-invariant; fold (1/8)*log2(e)
  const float qscale = 0.18033688011112042f;
  short8 qf[4][2];
#pragma unroll
  for (int nt = 0; nt < 4; nt++)
#pragma unroll
    for (int kc = 0; kc < 2; kc++) {
      const float* qp = q + ((size_t)b * 4096 + q0 + nt * 16 + c) * 64 + kc * 32 + quad * 8;
      floatx4 f0 = *(const floatx4*)qp;
      floatx4 f1 = *(const floatx4*)(qp + 4);
      short8 s;
#pragma unroll
      for (int j = 0; j < 4; j++) {
        s[j] = (short)f2bf(f0[j] * qscale);
        s[4 + j] = (short)f2bf(f1[j] * qscale);
      }
      qf[nt][kc] = s;
    }

  floatx4 o[4][4], o_l[4];  // O^T[d=mt*16+quad*4+r][q=nt*16+c]; o_l rows all equal l
#pragma unroll
  for (int mt = 0; mt < 4; mt++)
#pragma unroll
    for (int nt = 0; nt < 4; nt++) o[mt][nt] = (floatx4){0.f, 0.f, 0.f, 0.f};
#pragma unroll
  for (int nt = 0; nt < 4; nt++) o_l[nt] = (floatx4){0.f, 0.f, 0.f, 0.f};

#if HAVE_K16
  short4v ones_a;
#pragma unroll
  for (int j = 0; j < 4; j++) ones_a[j] = (short)0x3F80;
#else
  short8 ones_a;
#pragma unroll
  for (int j = 0; j < 8; j++) ones_a[j] = (short)0x3F80;
#endif

  const int r8 = lane >> 3, cs8 = lane & 7;
  unsigned short* wbase = smem + wave * 4096;  // private: 2 bufs x (K 1024 | V 1024)
  // per-lane global srcs at tile 0 (both advance 4096 ushorts per 64-key tile)
  const unsigned short* gK0 = kB + (size_t)(wave * 16 + r8) * 64 + (cs8 ^ r8) * 8;
  const unsigned short* gV0 = vtB + (size_t)(lane >> 1) * 64 + wave * 16 + (lane & 1) * 8;

  auto stage = [&](int t, int buf) {
    unsigned short* Kd = wbase + buf * 2048;
    const unsigned short* gk = gK0 + (size_t)t * 4096;
    const unsigned short* gv = gV0 + (size_t)t * 4096;
    load_lds16(gk, Kd);                   // K window rows 0-7 (phys slot = logical^row&7)
    load_lds16(gk + 8 * 64, Kd + 512);    // K rows 8-15
    load_lds16(gv, Kd + 1024);            // V d 0-31 x wave's 16 keys
    load_lds16(gv + 32 * 64, Kd + 1536);  // V d 32-63
  };

  stage(0, 0);

  for (int t = 0; t < 64; t++) {
    if (t < 63) {
      stage(t + 1, (t + 1) & 1);
      WAIT_VM4();  // stage(t) landed; stage(t+1)'s 4 loads remain in flight
    } else {
      WAIT_VM0();
    }
    __builtin_amdgcn_sched_barrier(0);  // loads can't sink below / reads can't hoist above

    const unsigned short* Kb = wbase + (t & 1) * 2048;
    const unsigned short* Vb = Kb + 1024;

    // K A-frags (A[m=key=c][k=d]); phys slot = (kc*4+quad)^(c&7)  [2-way max, free]
    short8 kf[2];
#pragma unroll
    for (int kc = 0; kc < 2; kc++)
      kf[kc] = *(const short8*)(Kb + c * 64 + ((kc * 4 + quad) ^ (c & 7)) * 8);
    // V A-frags for K16 (A[m=d=mt*16+c][k=key=quad*4+j])  [b64]
    u32x2 vv[4];
#pragma unroll
    for (int mt = 0; mt < 4; mt++)
      vv[mt] = *(const u32x2*)(Vb + (mt * 16 + c) * 16 + quad * 4);

#pragma unroll
    for (int nt = 0; nt < 4; nt++) {
      floatx4 s = (floatx4){0.f, 0.f, 0.f, 0.f};
      s = MFMA_K32(kf[0], qf[nt][0], s);
      s = MFMA_K32(kf[1], qf[nt][1], s);
      // P^T[key=quad*4+r][q=nt*16+c] = exp2(s[r]); trunc via perm hi16 (r6-verified)
      u32 u0 = __builtin_bit_cast(u32, EXP2(s[0]));
      u32 u1 = __builtin_bit_cast(u32, EXP2(s[1]));
      u32 u2 = __builtin_bit_cast(u32, EXP2(s[2]));
      u32 u3 = __builtin_bit_cast(u32, EXP2(s[3]));
      u32 plo = __builtin_amdgcn_perm(u1, u0, 0x07060302u);
      u32 phi = __builtin_amdgcn_perm(u3, u2, 0x07060302u);
#if HAVE_K16
      short4v pf = __builtin_bit_cast(short4v, (u32x2){plo, phi});
#pragma unroll
      for (int mt = 0; mt < 4; mt++)
        o[mt][nt] = MFMA_K16(__builtin_bit_cast(short4v, vv[mt]), pf, o[mt][nt]);
      o_l[nt] = MFMA_K16(ones_a, pf, o_l[nt]);  // l rows: Sum_k P^T[k][q]
#else
      short8 pf = __builtin_bit_cast(short8, (u32x4){plo, phi, 0u, 0u});
#pragma unroll
      for (int mt = 0; mt < 4; mt++) {
        short8 va = __builtin_bit_cast(short8, (u32x4){vv[mt][0], vv[mt][1], 0u, 0u});
        o[mt][nt] = MFMA_K32(va, pf, o[mt][nt]);
      }
      o_l[nt] = MFMA_K32(ones_a, pf, o_l[nt]);
#endif
    }
  }

  // ---- merge 4 wave-partials (first barriers since loop start) ----
  __syncthreads();  // all waves done with loop LDS; reuse as merge buffers
  float* obuf = (float*)smem_raw;  // 2 x [64 q][72]
  float* lbuf = obuf + 9216;       // [4 waves][64 q]
  if (lane < 16) {
#pragma unroll
    for (int nt = 0; nt < 4; nt++) lbuf[wave * 64 + nt * 16 + c] = o_l[nt][0];
  }
  if (wave < 2) {
    float* ob = obuf + wave * 4608;
#pragma unroll
    for (int mt = 0; mt < 4; mt++)
#pragma unroll
      for (int nt = 0; nt < 4; nt++)
        *(floatx4*)(ob + (nt * 16 + c) * 72 + mt * 16 + quad * 4) = o[mt][nt];
  }
  __syncthreads();
  if (wave >= 2) {
    float* ob = obuf + (wave - 2) * 4608;
#pragma unroll
    for (int mt = 0; mt < 4; mt++)
#pragma unroll
      for (int nt = 0; nt < 4; nt++) {
        float* a = ob + (nt * 16 + c) * 72 + mt * 16 + quad * 4;
        floatx4 cur = *(floatx4*)a;
        *(floatx4*)a = cur + o[mt][nt];
      }
  }
  __syncthreads();

  // out = O/l * mask, coalesced float4 stores
  const int row = tid >> 2, dg = (tid & 3) * 16;
  const float l = lbuf[row] + lbuf[64 + row] + lbuf[128 + row] + lbuf[192 + row];
  const float sc = mask[b * 4096 + q0 + row] / l;
  float* op = out + ((size_t)b * 4096 + q0 + row) * 64 + dg;
#pragma unroll
  for (int i = 0; i < 4; i++) {
    floatx4 a = *(const floatx4*)(obuf + row * 72 + dg + i * 4);
    floatx4 b2 = *(const floatx4*)(obuf + 4608 + row * 72 + dg + i * 4);
    *(floatx4*)(op + i * 4) = (a + b2) * sc;
  }
}

extern "C" void kernel_launch(void* const* d_in, const int* in_sizes, int n_in,
                              void* d_out, int out_size, void* d_ws, size_t ws_size,
                              hipStream_t stream) {
  const float* q = (const float*)d_in[0];
  const float* k = (const float*)d_in[1];
  const float* v = (const float*)d_in[2];
  const float* mask = (const float*)d_in[3];
  unsigned short* kb = (unsigned short*)d_ws;  // 4 MB
  unsigned short* vt = kb + 8 * 4096 * 64;     // 4 MB (needs ws >= 8 MB)
  prep_kv<<<512, 256, 0, stream>>>(k, v, kb, vt);
  attn<<<512, 256, 0, stream>>>(q, kb, vt, mask, (float*)d_out);
}